// Round 4
// baseline (650.682 us; speedup 1.0000x reference)
//
#include <hip/hip_runtime.h>
#include <hip/hip_bf16.h>
#include <hip/hip_cooperative_groups.h>

namespace cg = cooperative_groups;

// Sparse 3^3 conv x2 + LayerNorm + ReLU + residual. N=400000, C=32, K=27.
// Contract: ALL float inputs are FLOAT32, output f32, nbr int32.
// Workspace: h (bf16, 25.6MB) at d_ws+0; xb (bf16 copy of x) at +25.6MB.
//
// Round-4 (post-mortem r3: occupancy 30->51% bought NOTHING, 82->90us/pass --
// not occupancy-bound; revert to r2 64-vox/wave inner loop. End-to-end
// accounting across r0/r2/r3 shows ~40-50us of harness overhead PER KERNEL
// BOUNDARY (dur - sum(dispatch dur): 38us@2k, 100us@3k, 98us@3k). Biggest
// recoverable cost. Fix: ONE persistent cooperative kernel, 3 phases
// [xcvt | conv1 | conv2+resid] with grid.sync() between; 512 blocks x 512
// thr, co-residency guaranteed (LDS 53248 -> 3 blocks/CU cap, launch_bounds
// caps regs at 128 -> 4). B-table fill amortized: once per phase per block.
// Fallback to the proven r2 3-kernel path if cooperative launch is refused.)

#define NV   400000
#define NT   782        // ceil(NV / 512) tiles of 512 voxels
#define NBLK 512        // persistent blocks (2/CU, guaranteed co-resident)

typedef __bf16 bf16x8 __attribute__((ext_vector_type(8)));
typedef float  f32x4  __attribute__((ext_vector_type(4)));

union ABu { bf16x8 v; int4 i4; unsigned short us[8]; };

__device__ __forceinline__ unsigned short rb_f2bf(float f) {
    unsigned int u = __float_as_uint(f);
    return (unsigned short)((u + 0x7fffu + ((u >> 16) & 1u)) >> 16);
}

// k index for the 26 non-center offsets (skips k=13, the identity offset)
#define KIDX(kk) ((kk) + ((kk) >= 13 ? 1 : 0))

#define MFMA_BF16 __builtin_amdgcn_mfma_f32_16x16x32_bf16

// ---- shared building blocks -------------------------------------------------

// Fill LDS B-table for the 26 non-center offsets from f32 weights.
// Bp[kk*1024 + f*512 + lane*8 + j] = W[k][ci=(lane>>4)*8+j][co=(lane&15)+16f]
__device__ __forceinline__ void fill_btable(unsigned short* Bp,
                                            const float* __restrict__ Wf)
{
    for (int e = threadIdx.x; e < 26 * 1024; e += 512) {
        int kk = e >> 10;
        int k  = KIDX(kk);
        int r  = e & 1023;
        int f  = r >> 9;
        int ll = (r >> 3) & 63;
        int j  = r & 7;
        int ci = ((ll >> 4) << 3) + j;
        int co = (ll & 15) + (f << 4);
        Bp[e] = rb_f2bf(Wf[k * 1024 + ci * 32 + co]);
    }
}

// Center-offset (k=13, identity map) B fragments -> registers.
__device__ __forceinline__ void load_center(ABu& cb0, ABu& cb1,
                                            const float* __restrict__ Wf,
                                            int q, int n)
{
    #pragma unroll
    for (int j = 0; j < 8; ++j) {
        int ci = (q << 3) + j;
        cb0.us[j] = rb_f2bf(Wf[13 * 1024 + ci * 32 + n]);
        cb1.us[j] = rb_f2bf(Wf[13 * 1024 + ci * 32 + n + 16]);
    }
}

// Gather the 4 tile-slots for one offset from a wave-wide index register.
// jall lane l holds nbr index of voxel i0+l; tile t row n needs lane t*16+n.
#define GATHER4(gbuf, jall)                                                   \
    do {                                                                      \
        _Pragma("unroll")                                                     \
        for (int _t = 0; _t < 4; ++_t) {                                      \
            int _j = __shfl((jall), _t * 16 + n);                             \
            gbuf[_t] = make_int4(0, 0, 0, 0);                                 \
            if (_j >= 0)                                                      \
                gbuf[_t] = *(const int4*)(gsrc + ((size_t)_j << 5) + qo);     \
        }                                                                     \
    } while (0)

// Consume one offset's gather buffer: 2 LDS B-frag reads + 8 MFMAs.
#define CONSUME(kk, gbuf)                                                     \
    do {                                                                      \
        ABu _b0, _b1;                                                         \
        _b0.i4 = *(const int4*)(Bp + (kk) * 1024 + lane * 8);                 \
        _b1.i4 = *(const int4*)(Bp + (kk) * 1024 + 512 + lane * 8);           \
        _Pragma("unroll")                                                     \
        for (int _t = 0; _t < 4; ++_t) {                                      \
            ABu _a; _a.i4 = gbuf[_t];                                         \
            acc[_t][0] = MFMA_BF16(_a.v, _b0.v, acc[_t][0], 0, 0, 0);         \
            acc[_t][1] = MFMA_BF16(_a.v, _b1.v, acc[_t][1], 0, 0, 0);         \
        }                                                                     \
    } while (0)

#define NBLOAD(kk)                                                            \
    (okv ? __builtin_nontemporal_load(nbr + (size_t)KIDX(kk) * NV + v64) : -1)

// One conv+LN pass over tiles [start, NT) step stride. r2-proven inner loop:
// 64 vox/wave, named gA/gB double-buffered gathers, 2-pair index prefetch.
// WRITE_OUT=false: h(bf16) = relu(LN(conv(gsrc)))
// WRITE_OUT=true : out(f32) = relu(LN(conv(gsrc)) + x)
template <bool WRITE_OUT>
__device__ __forceinline__ void conv_pass(
    int start, int stride,
    const unsigned short* Bp,          // LDS B-table (filled + synced)
    ABu cb0, ABu cb1,                  // center B-frags
    const float* __restrict__ xf,      // residual source (pass 2)
    const int*   __restrict__ nbr,
    const float* __restrict__ gf,
    const float* __restrict__ bfv,
    float*       __restrict__ outf,
    unsigned short* __restrict__ hbuf,
    const unsigned short* __restrict__ gsrc)
{
    const int lane = threadIdx.x & 63;
    const int wv   = threadIdx.x >> 6;
    const int q    = lane >> 4, n = lane & 15;
    const int qo   = q * 8;
    const float gv0 = gf[n],  gv1 = gf[n + 16];
    const float bv0 = bfv[n], bv1 = bfv[n + 16];

    for (int tile = start; tile < NT; tile += stride) {
        const int  i0  = tile * 512 + wv * 64;     // 64 voxels per wave
        const int  v64 = i0 + lane;
        const bool okv = v64 < NV;

        f32x4 acc[4][2];
        #pragma unroll
        for (int t = 0; t < 4; ++t) {
            acc[t][0] = (f32x4){0.f, 0.f, 0.f, 0.f};
            acc[t][1] = (f32x4){0.f, 0.f, 0.f, 0.f};
        }

        // prologue: indices kk=0,1; center self-rows; gathers kk=0,1; idx 2,3
        int jA = NBLOAD(0);
        int jB = NBLOAD(1);

        int4 cgb[4];
        #pragma unroll
        for (int t = 0; t < 4; ++t) {
            int vt = i0 + t * 16 + n;
            cgb[t] = make_int4(0, 0, 0, 0);
            if (vt < NV) cgb[t] = *(const int4*)(gsrc + ((size_t)vt << 5) + qo);
        }

        int4 gA[4], gB[4];
        GATHER4(gA, jA);                   // kk=0
        GATHER4(gB, jB);                   // kk=1

        int jE = NBLOAD(2);
        int jO = NBLOAD(3);

        #pragma unroll
        for (int t = 0; t < 4; ++t) {      // center MFMA (frees cgb)
            ABu a; a.i4 = cgb[t];
            acc[t][0] = MFMA_BF16(a.v, cb0.v, acc[t][0], 0, 0, 0);
            acc[t][1] = MFMA_BF16(a.v, cb1.v, acc[t][1], 0, 0, 0);
        }

        // main pipeline: 13 fully-unrolled pairs, all register names static.
        #pragma unroll
        for (int p = 0; p < 13; ++p) {
            int jE2 = -1, jO2 = -1;
            if (2 * p + 4 < 26) jE2 = NBLOAD(2 * p + 4);
            if (2 * p + 5 < 26) jO2 = NBLOAD(2 * p + 5);

            CONSUME(2 * p, gA);
            if (2 * p + 2 < 26) GATHER4(gA, jE);

            CONSUME(2 * p + 1, gB);
            if (2 * p + 3 < 26) GATHER4(gB, jO);

            jE = jE2; jO = jO2;
        }

        // epilogue. C/D layout: cout = lane&15 (+16 frag1), voxel row = q*4+r.
        #pragma unroll
        for (int t = 0; t < 4; ++t) {
            #pragma unroll
            for (int r = 0; r < 4; ++r) {
                float x0 = acc[t][0][r], x1 = acc[t][1][r];
                float s  = x0 + x1;
                float ss = x0 * x0 + x1 * x1;
                #pragma unroll
                for (int mm = 1; mm <= 8; mm <<= 1) {  // LN reduce, 16-lane group
                    s  += __shfl_xor(s, mm);
                    ss += __shfl_xor(ss, mm);
                }
                float mu  = s * (1.f / 32.f);
                float var = ss * (1.f / 32.f) - mu * mu;
                float rs  = rsqrtf(var + 1e-6f);
                int vv = i0 + t * 16 + q * 4 + r;
                if (vv < NV) {
                    float y0 = (x0 - mu) * rs * gv0 + bv0;
                    float y1 = (x1 - mu) * rs * gv1 + bv1;
                    if constexpr (WRITE_OUT) {
                        y0 += xf[(size_t)vv * 32 + n];
                        y1 += xf[(size_t)vv * 32 + n + 16];
                        outf[(size_t)vv * 32 + n]      = fmaxf(y0, 0.f);
                        outf[(size_t)vv * 32 + n + 16] = fmaxf(y1, 0.f);
                    } else {
                        hbuf[(size_t)vv * 32 + n]      = rb_f2bf(fmaxf(y0, 0.f));
                        hbuf[(size_t)vv * 32 + n + 16] = rb_f2bf(fmaxf(y1, 0.f));
                    }
                }
            }
        }
    }
}

// ---- fused persistent cooperative kernel -----------------------------------
__global__ __launch_bounds__(512, 4) void ResidualBlock_37452114821416_kernel(
    const float* __restrict__ xf,
    const int*   __restrict__ nbr,
    const float* __restrict__ W1f,
    const float* __restrict__ g1f,
    const float* __restrict__ b1f,
    const float* __restrict__ W2f,
    const float* __restrict__ g2f,
    const float* __restrict__ b2f,
    float*       __restrict__ outf,
    unsigned short* __restrict__ hbuf,
    unsigned short* __restrict__ xb)
{
    __shared__ __align__(16) unsigned short Bp[26 * 1024];
    cg::grid_group grid = cg::this_grid();

    const int q = (threadIdx.x & 63) >> 4;
    const int n = threadIdx.x & 15;

    // ---- phase 0: xb = bf16(x), grid-stride over 1.6M 8-float chunks ----
    for (size_t c = (size_t)blockIdx.x * 512 + threadIdx.x;
         c < (size_t)NV * 32 / 8; c += (size_t)NBLK * 512) {
        size_t i = c * 8;
        float4 p0 = *(const float4*)(xf + i);
        float4 p1 = *(const float4*)(xf + i + 4);
        ABu a;
        a.us[0] = rb_f2bf(p0.x); a.us[1] = rb_f2bf(p0.y);
        a.us[2] = rb_f2bf(p0.z); a.us[3] = rb_f2bf(p0.w);
        a.us[4] = rb_f2bf(p1.x); a.us[5] = rb_f2bf(p1.y);
        a.us[6] = rb_f2bf(p1.z); a.us[7] = rb_f2bf(p1.w);
        *(int4*)(xb + i) = a.i4;
    }
    grid.sync();

    // ---- phase 1: h = relu(LN(conv1(xb))) ----
    fill_btable(Bp, W1f);
    ABu cb0, cb1;
    load_center(cb0, cb1, W1f, q, n);
    __syncthreads();
    conv_pass<false>(blockIdx.x, NBLK, Bp, cb0, cb1,
                     xf, nbr, g1f, b1f, outf, hbuf, xb);
    grid.sync();

    // ---- phase 2: out = relu(LN(conv2(h)) + x) ----
    fill_btable(Bp, W2f);
    load_center(cb0, cb1, W2f, q, n);
    __syncthreads();
    conv_pass<true>(blockIdx.x, NBLK, Bp, cb0, cb1,
                    xf, nbr, g2f, b2f, outf, hbuf, hbuf);
}

// ---- fallback wrappers (r2-equivalent 3-kernel path) ------------------------

__global__ __launch_bounds__(512) void xcvt_kernel(const float* __restrict__ xf,
                                                   unsigned short* __restrict__ xb)
{
    size_t i = ((size_t)blockIdx.x * 512 + threadIdx.x) * 8;
    float4 p0 = *(const float4*)(xf + i);
    float4 p1 = *(const float4*)(xf + i + 4);
    ABu a;
    a.us[0] = rb_f2bf(p0.x); a.us[1] = rb_f2bf(p0.y);
    a.us[2] = rb_f2bf(p0.z); a.us[3] = rb_f2bf(p0.w);
    a.us[4] = rb_f2bf(p1.x); a.us[5] = rb_f2bf(p1.y);
    a.us[6] = rb_f2bf(p1.z); a.us[7] = rb_f2bf(p1.w);
    *(int4*)(xb + i) = a.i4;
}

template <bool WRITE_OUT>
__global__ __launch_bounds__(512, 4) void pass_kernel(
    const float* __restrict__ xf, const int* __restrict__ nbr,
    const float* __restrict__ Wf, const float* __restrict__ gf,
    const float* __restrict__ bfv, float* __restrict__ outf,
    unsigned short* __restrict__ hbuf, const unsigned short* __restrict__ gsrc)
{
    __shared__ __align__(16) unsigned short Bp[26 * 1024];
    fill_btable(Bp, Wf);
    ABu cb0, cb1;
    load_center(cb0, cb1, Wf, (threadIdx.x & 63) >> 4, threadIdx.x & 15);
    __syncthreads();
    conv_pass<WRITE_OUT>(blockIdx.x, gridDim.x, Bp, cb0, cb1,
                         xf, nbr, gf, bfv, outf, hbuf, gsrc);
}

// Fallback pass-1 for tiny workspace (no xb room): f32 gathers from x.
__global__ __launch_bounds__(512, 4) void pass1_f32_kernel(
    const float* __restrict__ xf, const int* __restrict__ nbr,
    const float* __restrict__ Wf, const float* __restrict__ gf,
    const float* __restrict__ bfv, unsigned short* __restrict__ hbuf)
{
    __shared__ __align__(16) unsigned short Bp[27 * 1024];
    for (int e = threadIdx.x; e < 27 * 1024; e += 512) {
        int k = e >> 10, r = e & 1023, f = r >> 9;
        int ll = (r >> 3) & 63, j = r & 7;
        int ci = ((ll >> 4) << 3) + j, co = (ll & 15) + (f << 4);
        Bp[e] = rb_f2bf(Wf[k * 1024 + ci * 32 + co]);
    }
    __syncthreads();
    const int lane = threadIdx.x & 63, wv = threadIdx.x >> 6;
    const int q = lane >> 4, n = lane & 15;
    const int i0 = blockIdx.x * 512 + wv * 64;
    f32x4 acc[4][2];
    #pragma unroll
    for (int t = 0; t < 4; ++t) { acc[t][0] = (f32x4){0,0,0,0}; acc[t][1] = (f32x4){0,0,0,0}; }
    for (int k = 0; k < 27; ++k) {
        ABu b0, b1;
        b0.i4 = *(const int4*)(Bp + k * 1024 + lane * 8);
        b1.i4 = *(const int4*)(Bp + k * 1024 + 512 + lane * 8);
        const int* nb = nbr + (size_t)k * NV;
        #pragma unroll
        for (int t = 0; t < 4; ++t) {
            int v = i0 + t * 16 + n;
            int jn = (v < NV) ? nb[v] : -1;
            if (__ballot(jn >= 0) == 0ull) continue;
            ABu a; a.i4 = make_int4(0, 0, 0, 0);
            if (jn >= 0) {
                const float* src = xf + (size_t)jn * 32 + q * 8;
                float4 p0 = *(const float4*)(src);
                float4 p1 = *(const float4*)(src + 4);
                a.us[0] = rb_f2bf(p0.x); a.us[1] = rb_f2bf(p0.y);
                a.us[2] = rb_f2bf(p0.z); a.us[3] = rb_f2bf(p0.w);
                a.us[4] = rb_f2bf(p1.x); a.us[5] = rb_f2bf(p1.y);
                a.us[6] = rb_f2bf(p1.z); a.us[7] = rb_f2bf(p1.w);
            }
            acc[t][0] = MFMA_BF16(a.v, b0.v, acc[t][0], 0, 0, 0);
            acc[t][1] = MFMA_BF16(a.v, b1.v, acc[t][1], 0, 0, 0);
        }
    }
    const float gv0 = gf[n], gv1 = gf[n + 16];
    const float bv0 = bfv[n], bv1 = bfv[n + 16];
    #pragma unroll
    for (int t = 0; t < 4; ++t) {
        #pragma unroll
        for (int r = 0; r < 4; ++r) {
            float x0 = acc[t][0][r], x1 = acc[t][1][r];
            float s = x0 + x1, ss = x0 * x0 + x1 * x1;
            #pragma unroll
            for (int mm = 1; mm <= 8; mm <<= 1) { s += __shfl_xor(s, mm); ss += __shfl_xor(ss, mm); }
            float mu = s * (1.f / 32.f);
            float var = ss * (1.f / 32.f) - mu * mu;
            float rs = rsqrtf(var + 1e-6f);
            int vv = i0 + t * 16 + q * 4 + r;
            if (vv < NV) {
                float y0 = (x0 - mu) * rs * gv0 + bv0;
                float y1 = (x1 - mu) * rs * gv1 + bv1;
                hbuf[(size_t)vv * 32 + n]      = rb_f2bf(fmaxf(y0, 0.f));
                hbuf[(size_t)vv * 32 + n + 16] = rb_f2bf(fmaxf(y1, 0.f));
            }
        }
    }
}

extern "C" void kernel_launch(void* const* d_in, const int* in_sizes, int n_in,
                              void* d_out, int out_size, void* d_ws, size_t ws_size,
                              hipStream_t stream)
{
    // setup_inputs() dict order: x, nbr, W1, g1, b1, W2, g2, b2 — all f32 except nbr
    const float* x   = (const float*)d_in[0];
    const int*   nbr = (const int*)d_in[1];
    const float* W1  = (const float*)d_in[2];
    const float* g1  = (const float*)d_in[3];
    const float* b1  = (const float*)d_in[4];
    const float* W2  = (const float*)d_in[5];
    const float* g2  = (const float*)d_in[6];
    const float* b2  = (const float*)d_in[7];
    float* out = (float*)d_out;

    unsigned short* h  = (unsigned short*)d_ws;              // 25.6 MB
    unsigned short* xb = h + (size_t)NV * 32;                // +25.6 MB
    const bool have_xb = ws_size >= (size_t)NV * 32 * 2 * 2; // 51.2 MB needed

    if (have_xb) {
        void* kargs[] = {
            (void*)&x, (void*)&nbr, (void*)&W1, (void*)&g1, (void*)&b1,
            (void*)&W2, (void*)&g2, (void*)&b2, (void*)&out, (void*)&h,
            (void*)&xb
        };
        hipError_t ce = hipLaunchCooperativeKernel(
            (const void*)ResidualBlock_37452114821416_kernel,
            dim3(NBLK), dim3(512), kargs, 0, stream);
        if (ce == hipSuccess) {
            (void)in_sizes; (void)n_in; (void)out_size;
            return;
        }
        (void)hipGetLastError();   // clear, fall through to 3-kernel path
        xcvt_kernel<<<3125, 512, 0, stream>>>(x, xb);
        pass_kernel<false><<<NT, 512, 0, stream>>>(x, nbr, W1, g1, b1, out, h, xb);
    } else {
        pass1_f32_kernel<<<NT, 512, 0, stream>>>(x, nbr, W1, g1, b1, h);
    }
    pass_kernel<true><<<NT, 512, 0, stream>>>(x, nbr, W2, g2, b2, out, h, h);

    (void)in_sizes; (void)n_in; (void)out_size;
}

// Round 5
// 445.652 us; speedup vs baseline: 1.4601x; 1.4601x over previous
//
#include <hip/hip_runtime.h>
#include <hip/hip_bf16.h>
#include <hip/hip_cooperative_groups.h>

namespace cg = cooperative_groups;

// Sparse 3^3 conv x2 + LayerNorm + ReLU + residual. N=400000, C=32, K=27.
// Contract: ALL float inputs are FLOAT32, output f32, nbr int32.
// Workspace: h (bf16, 25.6MB) at d_ws+0; xb (bf16 copy of x) at +25.6MB.
//
// Round-5 (post-mortem r4: fused cooperative kernel PASSED but spilled --
// VGPR capped at 64 by __launch_bounds__(512,4) while the r2 inner loop needs
// ~92 unified regs; gather buffers spilled inside the unrolled 13-pair loop:
// FETCH 509MB / WRITE 525MB vs ~235/~103 expected, 524us/dispatch.
// Fix: __launch_bounds__(512,2) -> 256-VGPR cap (no spill; ~100-128 expected,
// still 2 blocks/CU with 53KB LDS); center frags loaded inside conv_pass;
// grid sized by hipOccupancyMaxActiveBlocksPerMultiprocessor so cooperative
// launch is always co-resident. Fallback: proven r2 3-kernel path.)

#define NV   400000
#define NT   782        // ceil(NV / 512) tiles of 512 voxels

typedef __bf16 bf16x8 __attribute__((ext_vector_type(8)));
typedef float  f32x4  __attribute__((ext_vector_type(4)));

union ABu { bf16x8 v; int4 i4; unsigned short us[8]; };

__device__ __forceinline__ unsigned short rb_f2bf(float f) {
    unsigned int u = __float_as_uint(f);
    return (unsigned short)((u + 0x7fffu + ((u >> 16) & 1u)) >> 16);
}

// k index for the 26 non-center offsets (skips k=13, the identity offset)
#define KIDX(kk) ((kk) + ((kk) >= 13 ? 1 : 0))

#define MFMA_BF16 __builtin_amdgcn_mfma_f32_16x16x32_bf16

// ---- shared building blocks -------------------------------------------------

// Fill LDS B-table for the 26 non-center offsets from f32 weights.
// Bp[kk*1024 + f*512 + lane*8 + j] = W[k][ci=(lane>>4)*8+j][co=(lane&15)+16f]
__device__ __forceinline__ void fill_btable(unsigned short* Bp,
                                            const float* __restrict__ Wf)
{
    for (int e = threadIdx.x; e < 26 * 1024; e += 512) {
        int kk = e >> 10;
        int k  = KIDX(kk);
        int r  = e & 1023;
        int f  = r >> 9;
        int ll = (r >> 3) & 63;
        int j  = r & 7;
        int ci = ((ll >> 4) << 3) + j;
        int co = (ll & 15) + (f << 4);
        Bp[e] = rb_f2bf(Wf[k * 1024 + ci * 32 + co]);
    }
}

// Gather the 4 tile-slots for one offset from a wave-wide index register.
// jall lane l holds nbr index of voxel i0+l; tile t row n needs lane t*16+n.
#define GATHER4(gbuf, jall)                                                   \
    do {                                                                      \
        _Pragma("unroll")                                                     \
        for (int _t = 0; _t < 4; ++_t) {                                      \
            int _j = __shfl((jall), _t * 16 + n);                             \
            gbuf[_t] = make_int4(0, 0, 0, 0);                                 \
            if (_j >= 0)                                                      \
                gbuf[_t] = *(const int4*)(gsrc + ((size_t)_j << 5) + qo);     \
        }                                                                     \
    } while (0)

// Consume one offset's gather buffer: 2 LDS B-frag reads + 8 MFMAs.
#define CONSUME(kk, gbuf)                                                     \
    do {                                                                      \
        ABu _b0, _b1;                                                         \
        _b0.i4 = *(const int4*)(Bp + (kk) * 1024 + lane * 8);                 \
        _b1.i4 = *(const int4*)(Bp + (kk) * 1024 + 512 + lane * 8);           \
        _Pragma("unroll")                                                     \
        for (int _t = 0; _t < 4; ++_t) {                                      \
            ABu _a; _a.i4 = gbuf[_t];                                         \
            acc[_t][0] = MFMA_BF16(_a.v, _b0.v, acc[_t][0], 0, 0, 0);         \
            acc[_t][1] = MFMA_BF16(_a.v, _b1.v, acc[_t][1], 0, 0, 0);         \
        }                                                                     \
    } while (0)

#define NBLOAD(kk)                                                            \
    (okv ? __builtin_nontemporal_load(nbr + (size_t)KIDX(kk) * NV + v64) : -1)

// One conv+LN pass over tiles [start, NT) step stride. r2-proven inner loop:
// 64 vox/wave, named gA/gB double-buffered gathers, 2-pair index prefetch.
// WRITE_OUT=false: h(bf16) = relu(LN(conv(gsrc)))
// WRITE_OUT=true : out(f32) = relu(LN(conv(gsrc)) + x)
template <bool WRITE_OUT>
__device__ __forceinline__ void conv_pass(
    int start, int stride,
    const unsigned short* Bp,          // LDS B-table (filled + synced)
    const float* __restrict__ Wf,      // weights (for center k=13 frags)
    const float* __restrict__ xf,      // residual source (pass 2)
    const int*   __restrict__ nbr,
    const float* __restrict__ gf,
    const float* __restrict__ bfv,
    float*       __restrict__ outf,
    unsigned short* __restrict__ hbuf,
    const unsigned short* __restrict__ gsrc)
{
    const int lane = threadIdx.x & 63;
    const int wv   = threadIdx.x >> 6;
    const int q    = lane >> 4, n = lane & 15;
    const int qo   = q * 8;
    const float gv0 = gf[n],  gv1 = gf[n + 16];
    const float bv0 = bfv[n], bv1 = bfv[n + 16];

    // center-offset (k=13, identity map) B fragments -> registers
    ABu cb0, cb1;
    #pragma unroll
    for (int j = 0; j < 8; ++j) {
        int ci = (q << 3) + j;
        cb0.us[j] = rb_f2bf(Wf[13 * 1024 + ci * 32 + n]);
        cb1.us[j] = rb_f2bf(Wf[13 * 1024 + ci * 32 + n + 16]);
    }

    for (int tile = start; tile < NT; tile += stride) {
        const int  i0  = tile * 512 + wv * 64;     // 64 voxels per wave
        const int  v64 = i0 + lane;
        const bool okv = v64 < NV;

        f32x4 acc[4][2];
        #pragma unroll
        for (int t = 0; t < 4; ++t) {
            acc[t][0] = (f32x4){0.f, 0.f, 0.f, 0.f};
            acc[t][1] = (f32x4){0.f, 0.f, 0.f, 0.f};
        }

        // prologue: indices kk=0,1; center self-rows; gathers kk=0,1; idx 2,3
        int jA = NBLOAD(0);
        int jB = NBLOAD(1);

        int4 cgb[4];
        #pragma unroll
        for (int t = 0; t < 4; ++t) {
            int vt = i0 + t * 16 + n;
            cgb[t] = make_int4(0, 0, 0, 0);
            if (vt < NV) cgb[t] = *(const int4*)(gsrc + ((size_t)vt << 5) + qo);
        }

        int4 gA[4], gB[4];
        GATHER4(gA, jA);                   // kk=0
        GATHER4(gB, jB);                   // kk=1

        int jE = NBLOAD(2);
        int jO = NBLOAD(3);

        #pragma unroll
        for (int t = 0; t < 4; ++t) {      // center MFMA (frees cgb)
            ABu a; a.i4 = cgb[t];
            acc[t][0] = MFMA_BF16(a.v, cb0.v, acc[t][0], 0, 0, 0);
            acc[t][1] = MFMA_BF16(a.v, cb1.v, acc[t][1], 0, 0, 0);
        }

        // main pipeline: 13 fully-unrolled pairs, all register names static.
        #pragma unroll
        for (int p = 0; p < 13; ++p) {
            int jE2 = -1, jO2 = -1;
            if (2 * p + 4 < 26) jE2 = NBLOAD(2 * p + 4);
            if (2 * p + 5 < 26) jO2 = NBLOAD(2 * p + 5);

            CONSUME(2 * p, gA);
            if (2 * p + 2 < 26) GATHER4(gA, jE);

            CONSUME(2 * p + 1, gB);
            if (2 * p + 3 < 26) GATHER4(gB, jO);

            jE = jE2; jO = jO2;
        }

        // epilogue. C/D layout: cout = lane&15 (+16 frag1), voxel row = q*4+r.
        #pragma unroll
        for (int t = 0; t < 4; ++t) {
            #pragma unroll
            for (int r = 0; r < 4; ++r) {
                float x0 = acc[t][0][r], x1 = acc[t][1][r];
                float s  = x0 + x1;
                float ss = x0 * x0 + x1 * x1;
                #pragma unroll
                for (int mm = 1; mm <= 8; mm <<= 1) {  // LN reduce, 16-lane group
                    s  += __shfl_xor(s, mm);
                    ss += __shfl_xor(ss, mm);
                }
                float mu  = s * (1.f / 32.f);
                float var = ss * (1.f / 32.f) - mu * mu;
                float rs  = rsqrtf(var + 1e-6f);
                int vv = i0 + t * 16 + q * 4 + r;
                if (vv < NV) {
                    float y0 = (x0 - mu) * rs * gv0 + bv0;
                    float y1 = (x1 - mu) * rs * gv1 + bv1;
                    if constexpr (WRITE_OUT) {
                        y0 += xf[(size_t)vv * 32 + n];
                        y1 += xf[(size_t)vv * 32 + n + 16];
                        outf[(size_t)vv * 32 + n]      = fmaxf(y0, 0.f);
                        outf[(size_t)vv * 32 + n + 16] = fmaxf(y1, 0.f);
                    } else {
                        hbuf[(size_t)vv * 32 + n]      = rb_f2bf(fmaxf(y0, 0.f));
                        hbuf[(size_t)vv * 32 + n + 16] = rb_f2bf(fmaxf(y1, 0.f));
                    }
                }
            }
        }
    }
}

// ---- fused persistent cooperative kernel -----------------------------------
// __launch_bounds__(512, 2): min 2 waves/EU -> 256-VGPR cap. The r2 inner
// loop needs ~92 unified regs; r4's (512,4) forced a 64-VGPR ceiling and
// spilled the gather pipeline (+400MB scratch traffic). 2 blocks/CU residency
// comes from LDS (53KB) + actual VGPR use, enforced at launch via the
// occupancy API, not via the bound.
__global__ __launch_bounds__(512, 2) void ResidualBlock_37452114821416_kernel(
    const float* __restrict__ xf,
    const int*   __restrict__ nbr,
    const float* __restrict__ W1f,
    const float* __restrict__ g1f,
    const float* __restrict__ b1f,
    const float* __restrict__ W2f,
    const float* __restrict__ g2f,
    const float* __restrict__ b2f,
    float*       __restrict__ outf,
    unsigned short* __restrict__ hbuf,
    unsigned short* __restrict__ xb)
{
    __shared__ __align__(16) unsigned short Bp[26 * 1024];
    cg::grid_group grid = cg::this_grid();

    // ---- phase 0: xb = bf16(x), grid-stride over 1.6M 8-float chunks ----
    for (size_t c = (size_t)blockIdx.x * 512 + threadIdx.x;
         c < (size_t)NV * 32 / 8; c += (size_t)gridDim.x * 512) {
        size_t i = c * 8;
        float4 p0 = *(const float4*)(xf + i);
        float4 p1 = *(const float4*)(xf + i + 4);
        ABu a;
        a.us[0] = rb_f2bf(p0.x); a.us[1] = rb_f2bf(p0.y);
        a.us[2] = rb_f2bf(p0.z); a.us[3] = rb_f2bf(p0.w);
        a.us[4] = rb_f2bf(p1.x); a.us[5] = rb_f2bf(p1.y);
        a.us[6] = rb_f2bf(p1.z); a.us[7] = rb_f2bf(p1.w);
        *(int4*)(xb + i) = a.i4;
    }
    __threadfence();
    grid.sync();

    // ---- phase 1: h = relu(LN(conv1(xb))) ----
    fill_btable(Bp, W1f);
    __syncthreads();
    conv_pass<false>(blockIdx.x, gridDim.x, Bp, W1f,
                     xf, nbr, g1f, b1f, outf, hbuf, xb);
    __threadfence();
    grid.sync();

    // ---- phase 2: out = relu(LN(conv2(h)) + x) ----
    __syncthreads();               // all waves past phase-1 Bp reads
    fill_btable(Bp, W2f);
    __syncthreads();
    conv_pass<true>(blockIdx.x, gridDim.x, Bp, W2f,
                    xf, nbr, g2f, b2f, outf, hbuf, hbuf);
}

// ---- fallback wrappers (r2-equivalent 3-kernel path) ------------------------

__global__ __launch_bounds__(512) void xcvt_kernel(const float* __restrict__ xf,
                                                   unsigned short* __restrict__ xb)
{
    size_t i = ((size_t)blockIdx.x * 512 + threadIdx.x) * 8;
    float4 p0 = *(const float4*)(xf + i);
    float4 p1 = *(const float4*)(xf + i + 4);
    ABu a;
    a.us[0] = rb_f2bf(p0.x); a.us[1] = rb_f2bf(p0.y);
    a.us[2] = rb_f2bf(p0.z); a.us[3] = rb_f2bf(p0.w);
    a.us[4] = rb_f2bf(p1.x); a.us[5] = rb_f2bf(p1.y);
    a.us[6] = rb_f2bf(p1.z); a.us[7] = rb_f2bf(p1.w);
    *(int4*)(xb + i) = a.i4;
}

template <bool WRITE_OUT>
__global__ __launch_bounds__(512, 2) void pass_kernel(
    const float* __restrict__ xf, const int* __restrict__ nbr,
    const float* __restrict__ Wf, const float* __restrict__ gf,
    const float* __restrict__ bfv, float* __restrict__ outf,
    unsigned short* __restrict__ hbuf, const unsigned short* __restrict__ gsrc)
{
    __shared__ __align__(16) unsigned short Bp[26 * 1024];
    fill_btable(Bp, Wf);
    __syncthreads();
    conv_pass<WRITE_OUT>(blockIdx.x, gridDim.x, Bp, Wf,
                         xf, nbr, gf, bfv, outf, hbuf, gsrc);
}

// Fallback pass-1 for tiny workspace (no xb room): f32 gathers from x.
__global__ __launch_bounds__(512, 4) void pass1_f32_kernel(
    const float* __restrict__ xf, const int* __restrict__ nbr,
    const float* __restrict__ Wf, const float* __restrict__ gf,
    const float* __restrict__ bfv, unsigned short* __restrict__ hbuf)
{
    __shared__ __align__(16) unsigned short Bp[27 * 1024];
    for (int e = threadIdx.x; e < 27 * 1024; e += 512) {
        int k = e >> 10, r = e & 1023, f = r >> 9;
        int ll = (r >> 3) & 63, j = r & 7;
        int ci = ((ll >> 4) << 3) + j, co = (ll & 15) + (f << 4);
        Bp[e] = rb_f2bf(Wf[k * 1024 + ci * 32 + co]);
    }
    __syncthreads();
    const int lane = threadIdx.x & 63, wv = threadIdx.x >> 6;
    const int q = lane >> 4, n = lane & 15;
    const int i0 = blockIdx.x * 512 + wv * 64;
    f32x4 acc[4][2];
    #pragma unroll
    for (int t = 0; t < 4; ++t) { acc[t][0] = (f32x4){0,0,0,0}; acc[t][1] = (f32x4){0,0,0,0}; }
    for (int k = 0; k < 27; ++k) {
        ABu b0, b1;
        b0.i4 = *(const int4*)(Bp + k * 1024 + lane * 8);
        b1.i4 = *(const int4*)(Bp + k * 1024 + 512 + lane * 8);
        const int* nb = nbr + (size_t)k * NV;
        #pragma unroll
        for (int t = 0; t < 4; ++t) {
            int v = i0 + t * 16 + n;
            int jn = (v < NV) ? nb[v] : -1;
            if (__ballot(jn >= 0) == 0ull) continue;
            ABu a; a.i4 = make_int4(0, 0, 0, 0);
            if (jn >= 0) {
                const float* src = xf + (size_t)jn * 32 + q * 8;
                float4 p0 = *(const float4*)(src);
                float4 p1 = *(const float4*)(src + 4);
                a.us[0] = rb_f2bf(p0.x); a.us[1] = rb_f2bf(p0.y);
                a.us[2] = rb_f2bf(p0.z); a.us[3] = rb_f2bf(p0.w);
                a.us[4] = rb_f2bf(p1.x); a.us[5] = rb_f2bf(p1.y);
                a.us[6] = rb_f2bf(p1.z); a.us[7] = rb_f2bf(p1.w);
            }
            acc[t][0] = MFMA_BF16(a.v, b0.v, acc[t][0], 0, 0, 0);
            acc[t][1] = MFMA_BF16(a.v, b1.v, acc[t][1], 0, 0, 0);
        }
    }
    const float gv0 = gf[n], gv1 = gf[n + 16];
    const float bv0 = bfv[n], bv1 = bfv[n + 16];
    #pragma unroll
    for (int t = 0; t < 4; ++t) {
        #pragma unroll
        for (int r = 0; r < 4; ++r) {
            float x0 = acc[t][0][r], x1 = acc[t][1][r];
            float s = x0 + x1, ss = x0 * x0 + x1 * x1;
            #pragma unroll
            for (int mm = 1; mm <= 8; mm <<= 1) { s += __shfl_xor(s, mm); ss += __shfl_xor(ss, mm); }
            float mu = s * (1.f / 32.f);
            float var = ss * (1.f / 32.f) - mu * mu;
            float rs = rsqrtf(var + 1e-6f);
            int vv = i0 + t * 16 + q * 4 + r;
            if (vv < NV) {
                float y0 = (x0 - mu) * rs * gv0 + bv0;
                float y1 = (x1 - mu) * rs * gv1 + bv1;
                hbuf[(size_t)vv * 32 + n]      = rb_f2bf(fmaxf(y0, 0.f));
                hbuf[(size_t)vv * 32 + n + 16] = rb_f2bf(fmaxf(y1, 0.f));
            }
        }
    }
}

extern "C" void kernel_launch(void* const* d_in, const int* in_sizes, int n_in,
                              void* d_out, int out_size, void* d_ws, size_t ws_size,
                              hipStream_t stream)
{
    // setup_inputs() dict order: x, nbr, W1, g1, b1, W2, g2, b2 — all f32 except nbr
    const float* x   = (const float*)d_in[0];
    const int*   nbr = (const int*)d_in[1];
    const float* W1  = (const float*)d_in[2];
    const float* g1  = (const float*)d_in[3];
    const float* b1  = (const float*)d_in[4];
    const float* W2  = (const float*)d_in[5];
    const float* g2  = (const float*)d_in[6];
    const float* b2  = (const float*)d_in[7];
    float* out = (float*)d_out;

    unsigned short* h  = (unsigned short*)d_ws;              // 25.6 MB
    unsigned short* xb = h + (size_t)NV * 32;                // +25.6 MB
    const bool have_xb = ws_size >= (size_t)NV * 32 * 2 * 2; // 51.2 MB needed

    // Co-residency capacity for the fused kernel (host-side query, cached).
    static int g_bpc = -2;   // -2 = not queried
    if (g_bpc == -2) {
        int bpc = 0;
        hipError_t oe = hipOccupancyMaxActiveBlocksPerMultiprocessor(
            &bpc, (const void*)ResidualBlock_37452114821416_kernel, 512, 0);
        g_bpc = (oe == hipSuccess) ? bpc : 0;
        (void)hipGetLastError();
    }

    if (have_xb && g_bpc >= 1) {
        const int nblk = (g_bpc < 3 ? g_bpc : 3) * 256;   // co-resident grid
        void* kargs[] = {
            (void*)&x, (void*)&nbr, (void*)&W1, (void*)&g1, (void*)&b1,
            (void*)&W2, (void*)&g2, (void*)&b2, (void*)&out, (void*)&h,
            (void*)&xb
        };
        hipError_t ce = hipLaunchCooperativeKernel(
            (const void*)ResidualBlock_37452114821416_kernel,
            dim3(nblk), dim3(512), kargs, 0, stream);
        if (ce == hipSuccess) {
            (void)in_sizes; (void)n_in; (void)out_size;
            return;
        }
        (void)hipGetLastError();   // clear, fall through to 3-kernel path
    }

    if (have_xb) {
        xcvt_kernel<<<3125, 512, 0, stream>>>(x, xb);
        pass_kernel<false><<<NT, 512, 0, stream>>>(x, nbr, W1, g1, b1, out, h, xb);
    } else {
        pass1_f32_kernel<<<NT, 512, 0, stream>>>(x, nbr, W1, g1, b1, h);
    }
    pass_kernel<true><<<NT, 512, 0, stream>>>(x, nbr, W2, g2, b2, out, h, h);

    (void)in_sizes; (void)n_in; (void)out_size;
}